// Round 2
// baseline (682.327 us; speedup 1.0000x reference)
//
#include <hip/hip_runtime.h>

#define SR 4
#define DD 9          // 2*SR+1
#define NIDX 81
#define HH 128
#define WW 128
#define CC 128
#define ROWS 4        // pixel rows per block
#define COLS 136      // WW + 2*SR (padded)
#define PPX 8         // pixels per lane-group
#define CHUNKC 32     // channels staged per phase
#define NCH (CC / CHUNKC)          // 4 chunk phases
#define C4S (CHUNKC / 4)           // 8 float4-blocks per cell
#define LDS_F4 (ROWS * COLS * C4S) // 4352 float4 = 69632 B (static, 2 blocks/CU)

__global__ __launch_bounds__(256, 2)
void cost_volume_kernel(const float* __restrict__ x1,
                        const float* __restrict__ x2,
                        float* __restrict__ out) {
    __shared__ float4 x2s4[LDS_F4];
    float* x2s = (float*)x2s4;

    const int tid  = threadIdx.x;
    const int wave = tid >> 6;        // 0..3  -> pixel row within strip
    const int lane = tid & 63;
    const int gl   = lane & 15;       // pixel group within row
    const int q    = lane >> 4;       // 4-way channel split

    const int b    = blockIdx.x >> 5;          // batch
    const int h0   = (blockIdx.x & 31) * ROWS; // strip base row
    const int half = blockIdx.y;               // i-range half

    const int row = wave;
    const int w0  = gl * PPX;

    const float* x1p = x1 + ((size_t)((b * HH + h0 + row) * WW + w0)) * CC;
    const float* x2b = x2 + (size_t)b * HH * WW * CC;
    float* outp = out + ((size_t)((b * HH + h0 + row) * WW)) * NIDX;

    const int c4w      = tid & (C4S - 1);   // staging: float4-block id (0..7)
    const int stage_hi = tid >> 3;          // staging: cell sub-id (0..31)

    const int i_lo = half ? 1 : -SR;
    const int i_hi = half ? SR : 0;

    for (int i = i_lo; i <= i_hi; ++i) {
        float acc[PPX][DD];
        #pragma unroll
        for (int p = 0; p < PPX; ++p)
            #pragma unroll
            for (int j = 0; j < DD; ++j) acc[p][j] = 0.f;

        for (int ch = 0; ch < NCH; ++ch) {
            const int cbase = ch * CHUNKC;
            __syncthreads();   // previous phase fully consumed before overwrite
            // ---- stage x2 rows (h0 + r - i), padded cols, channels [cbase, cbase+32) ----
            // cells: 4 rows * 136 cols = 544; * 8 f4-blocks = 4352 = 256 threads * 17
            for (int k = 0; k < 17; ++k) {
                int tmp = stage_hi + (k << 5);      // 0..543 == r*136 + ps
                int r   = tmp / COLS;
                int ps  = tmp - r * COLS;
                int hp  = h0 + r - i;
                int wp  = ps - SR;
                float4 v = make_float4(0.f, 0.f, 0.f, 0.f);
                if ((unsigned)hp < (unsigned)HH && (unsigned)wp < (unsigned)WW)
                    v = *(const float4*)(x2b + (size_t)(hp * WW + wp) * CC + cbase + 4 * c4w);
                int slot4 = tmp * C4S + (c4w ^ ((ps >> 3) & 7));
                x2s4[slot4] = v;
            }
            __syncthreads();
            // ---- compute: 2 t-slices of 4 channels each (c-split q interleaved by 4) ----
            #pragma unroll
            for (int t = 0; t < 2; ++t) {
                const int cl  = 16 * t + 4 * q;   // c_local within chunk
                const int c4v = 4 * t + q;        // float4-block index (0..7)

                float4 a[PPX];
                #pragma unroll
                for (int p = 0; p < PPX; ++p)
                    a[p] = *(const float4*)(x1p + p * CC + cbase + cl);

                float4 v[16];
                #pragma unroll
                for (int d = 0; d < 16; ++d) {
                    int ps    = w0 + d;
                    int slot4 = (row * COLS + ps) * C4S + (c4v ^ ((ps >> 3) & 7));
                    v[d] = x2s4[slot4];
                }

                #pragma unroll
                for (int p = 0; p < PPX; ++p) {
                    #pragma unroll
                    for (int j = 0; j < DD; ++j) {
                        // output (w0+p, shift j-4) needs x2 col (w0+p)-(j-4) -> window idx p+8-j
                        const float4 xv = v[p + 8 - j];
                        float s = acc[p][j];
                        s = fmaf(a[p].x, xv.x, s);
                        s = fmaf(a[p].y, xv.y, s);
                        s = fmaf(a[p].z, xv.z, s);
                        s = fmaf(a[p].w, xv.w, s);
                        acc[p][j] = s;
                    }
                }
            }
        }

        // ---- reduce the 4-way c-split (lanes l, l^16, l^32, l^48 share a pixel group) ----
        #pragma unroll
        for (int p = 0; p < PPX; ++p) {
            #pragma unroll
            for (int j = 0; j < DD; ++j) {
                float s = acc[p][j];
                s += __shfl_xor(s, 16, 64);
                s += __shfl_xor(s, 32, 64);
                acc[p][j] = s;
            }
        }

        // ---- store: q-lane stores pixels p = 2q, 2q+1 (static acc indexing) ----
        const float inv = 1.0f / (float)HH;
        #pragma unroll
        for (int p = 0; p < PPX; ++p) {
            if ((p >> 1) == q) {
                float* op = outp + (size_t)(w0 + p) * NIDX;
                #pragma unroll
                for (int j = 0; j < DD; ++j) {
                    int idx = 9 * i + (j - SR);   // torch negative-index wrap
                    if (idx < 0) idx += NIDX;
                    op[idx] = acc[p][j] * inv;
                }
            }
        }
    }
}

extern "C" void kernel_launch(void* const* d_in, const int* in_sizes, int n_in,
                              void* d_out, int out_size, void* d_ws, size_t ws_size,
                              hipStream_t stream) {
    const float* x1 = (const float*)d_in[0];
    const float* x2 = (const float*)d_in[1];
    float* out = (float*)d_out;
    (void)in_sizes; (void)n_in; (void)out_size; (void)d_ws; (void)ws_size;

    dim3 grid(256, 2);   // 256 (b, 4-row strip) x 2 i-range halves = 512 = 2 blocks/CU
    dim3 block(256);
    hipLaunchKernelGGL(cost_volume_kernel, grid, block, 0, stream, x1, x2, out);
}